// Round 3
// baseline (232.775 us; speedup 1.0000x reference)
//
#include <hip/hip_runtime.h>

// EMA along T: y[b,c,0] = x[b,c,0]; y[b,c,t] = s*x[t] + (1-s)*y[t-1]
// x: [B, C, T] f32, weights: [C] f32 (clamped to [0,1]).
// B=16, C=512, T=4096.

constexpr int T_LEN = 4096;
constexpr int C_LEN = 512;
constexpr int BLOCK = 256;
constexpr int PER_THREAD = T_LEN / BLOCK;   // 16

__global__ __launch_bounds__(BLOCK) void ema_scan_kernel(
    const float* __restrict__ x,
    const float* __restrict__ w,
    float* __restrict__ y)
{
    const int row  = blockIdx.x;          // b*C + c
    const int c    = row & (C_LEN - 1);   // C=512 is pow2
    const int tid  = threadIdx.x;
    const int lane = tid & 63;
    const int wave = tid >> 6;

    float s = w[c];
    s = fminf(fmaxf(s, 0.0f), 1.0f);
    const float a = 1.0f - s;

    const float* xr = x + (size_t)row * T_LEN + tid * PER_THREAD;
    float*       yr = y + (size_t)row * T_LEN + tid * PER_THREAD;

    // ---- load 16 contiguous floats (4 x float4) ----
    float4 v0 = ((const float4*)xr)[0];
    float4 v1 = ((const float4*)xr)[1];
    float4 v2 = ((const float4*)xr)[2];
    float4 v3 = ((const float4*)xr)[3];

    float l[PER_THREAD];
    l[0]=v0.x; l[1]=v0.y; l[2]=v0.z;  l[3]=v0.w;
    l[4]=v1.x; l[5]=v1.y; l[6]=v1.z;  l[7]=v1.w;
    l[8]=v2.x; l[9]=v2.y; l[10]=v2.z; l[11]=v2.w;
    l[12]=v3.x;l[13]=v3.y;l[14]=v3.z; l[15]=v3.w;

    // ---- local serial scan with zero initial condition ----
    // l_j = s*x_j + a*l_{j-1}, l_{-1} = 0.
    // Thread 0 element 0 is special: y0 = x0 (identity, no smoothing).
    float acc = (tid == 0) ? l[0] : s * l[0];
    l[0] = acc;
    #pragma unroll
    for (int j = 1; j < PER_THREAD; ++j) {
        float t = s * l[j];          // independent of the chain
        acc = fmaf(a, acc, t);       // 4-cyc dependent fma chain, 15 deep
        l[j] = acc;
    }
    // acc == b_i : this thread's outgoing value assuming zero input carry
    // (exact for thread 0 since y0=x0 kills any incoming dependence).

    // a^16 by squaring
    float a2 = a * a;
    float a4 = a2 * a2;
    float a8 = a4 * a4;
    const float a16 = a8 * a8;

    // ---- in-wave weighted inclusive scan of b over 64 lanes ----
    // S_l = sum_{j<=l} a16^(l-j) * b_j  (Hillis-Steele, weight squares per step)
    float S = acc;
    float wgt = a16;
    #pragma unroll
    for (int d = 1; d < 64; d <<= 1) {
        float up = __shfl_up(S, d, 64);
        if (lane >= d) S = fmaf(wgt, up, S);
        wgt *= wgt;
    }

    // ---- cross-wave carry via LDS (4 wave totals) ----
    __shared__ float tot[4];
    if (lane == 63) tot[wave] = S;
    __syncthreads();

    // a16^64
    float a64 = a16;
    #pragma unroll
    for (int k = 0; k < 6; ++k) a64 *= a64;

    float Cw = 0.0f;     // carry entering this wave
    {
        float f = 1.0f;
        for (int u = wave - 1; u >= 0; --u) {
            Cw = fmaf(f, tot[u], Cw);
            f *= a64;
        }
    }

    // ---- exclusive prefix for this thread ----
    // P_i = S_{i-1} = (lane==0 ? 0 : S[lane-1]) + a16^lane * Cw
    float Sx = __shfl_up(S, 1, 64);
    float P_local = (lane == 0) ? 0.0f : Sx;
    float powl = 1.0f, tq = a16;
    #pragma unroll
    for (int bit = 0; bit < 6; ++bit) {
        if ((lane >> bit) & 1) powl *= tq;
        tq *= tq;
    }
    const float P = fmaf(powl, Cw, P_local);   // thread 0: 0

    // ---- fixup: y_j = l_j + a^(j+1) * P ----
    float aj = a;
    #pragma unroll
    for (int j = 0; j < PER_THREAD; ++j) {
        l[j] = fmaf(aj, P, l[j]);
        aj *= a;
    }

    // ---- store 4 x float4 ----
    float4 o0 = make_float4(l[0],  l[1],  l[2],  l[3]);
    float4 o1 = make_float4(l[4],  l[5],  l[6],  l[7]);
    float4 o2 = make_float4(l[8],  l[9],  l[10], l[11]);
    float4 o3 = make_float4(l[12], l[13], l[14], l[15]);
    ((float4*)yr)[0] = o0;
    ((float4*)yr)[1] = o1;
    ((float4*)yr)[2] = o2;
    ((float4*)yr)[3] = o3;
}

extern "C" void kernel_launch(void* const* d_in, const int* in_sizes, int n_in,
                              void* d_out, int out_size, void* d_ws, size_t ws_size,
                              hipStream_t stream) {
    const float* x = (const float*)d_in[0];
    const float* w = (const float*)d_in[1];
    float* y = (float*)d_out;

    const int rows = out_size / T_LEN;   // B*C = 8192
    ema_scan_kernel<<<rows, BLOCK, 0, stream>>>(x, w, y);
}

// Round 4
// 224.109 us; speedup vs baseline: 1.0387x; 1.0387x over previous
//
#include <hip/hip_runtime.h>

// EMA along T: y[t] = s*x[t] + (1-s)*y[t-1], y[0] = x[0].
// x: [B, C, T] f32, weights: [C] f32 (clamped to [0,1]). B=16, C=512, T=4096.
//
// Decomposition: one 1024-thread block per row; each thread owns ONE float4
// (4 contiguous elements) so every global load/store is perfectly coalesced
// (lane i at base+16*i). Scan: 3-FMA local scan -> 64-lane weighted shuffle
// scan (step weight a^4) -> 16-entry LDS cross-wave carry (weight a^256) ->
// per-element fixup y_j = l_j + a^(j+1) * P.

constexpr int T_LEN = 4096;
constexpr int C_LEN = 512;
constexpr int BLOCK = 1024;          // = T_LEN / 4 threads per row
constexpr int NWAVES = BLOCK / 64;   // 16

__global__ __launch_bounds__(BLOCK) void ema_scan_kernel(
    const float* __restrict__ x,
    const float* __restrict__ w,
    float* __restrict__ y)
{
    const int row  = blockIdx.x;          // b*C + c
    const int c    = row & (C_LEN - 1);   // C=512 pow2
    const int tid  = threadIdx.x;
    const int lane = tid & 63;
    const int wave = tid >> 6;

    float s = w[c];
    s = fminf(fmaxf(s, 0.0f), 1.0f);
    const float a = 1.0f - s;

    const float4* xr = (const float4*)(x + (size_t)row * T_LEN) + tid;
    float4*       yr = (float4*)(y + (size_t)row * T_LEN) + tid;

    // ---- perfectly coalesced load: lane i reads 16B at base+16i ----
    float4 v = *xr;

    // ---- local serial scan over 4 elements, zero incoming carry ----
    // Thread 0 element 0 is the identity case: y0 = x0.
    float l0 = (tid == 0) ? v.x : s * v.x;
    float l1 = fmaf(a, l0, s * v.y);
    float l2 = fmaf(a, l1, s * v.z);
    float l3 = fmaf(a, l2, s * v.w);

    const float a2 = a * a;
    const float a3 = a2 * a;
    const float a4 = a2 * a2;

    // ---- in-wave weighted inclusive scan of thread totals (step wt a^4) ----
    float S = l3;
    float wgt = a4;
    #pragma unroll
    for (int d = 1; d < 64; d <<= 1) {
        float up = __shfl_up(S, d, 64);
        if (lane >= d) S = fmaf(wgt, up, S);
        wgt *= wgt;
    }
    const float a256 = wgt;   // a4 squared 6 times = a^256 (one wave's span)

    // ---- cross-wave carry via LDS (16 wave totals) ----
    __shared__ float tot[NWAVES];
    if (lane == 63) tot[wave] = S;
    __syncthreads();

    float Cw = 0.0f;          // carry entering this wave
    {
        float f = 1.0f;
        for (int u = wave - 1; u >= 0; --u) {  // <=15 iters; wave-uniform
            Cw = fmaf(f, tot[u], Cw);
            f *= a256;
        }
    }

    // ---- exclusive prefix for this thread ----
    // P = S[lane-1] + (a^4)^lane * Cw   (S[-1] = 0)
    float Sx = __shfl_up(S, 1, 64);
    float Pl = (lane == 0) ? 0.0f : Sx;
    float powl = 1.0f, tq = a4;
    #pragma unroll
    for (int b = 0; b < 6; ++b) {
        if ((lane >> b) & 1) powl *= tq;
        tq *= tq;
    }
    const float P = fmaf(powl, Cw, Pl);   // thread 0 of wave 0: 0

    // ---- fixup + perfectly coalesced store ----
    float4 o;
    o.x = fmaf(a,  P, l0);
    o.y = fmaf(a2, P, l1);
    o.z = fmaf(a3, P, l2);
    o.w = fmaf(a4, P, l3);
    *yr = o;
}

extern "C" void kernel_launch(void* const* d_in, const int* in_sizes, int n_in,
                              void* d_out, int out_size, void* d_ws, size_t ws_size,
                              hipStream_t stream) {
    const float* x = (const float*)d_in[0];
    const float* w = (const float*)d_in[1];
    float* y = (float*)d_out;

    const int rows = out_size / T_LEN;   // B*C = 8192
    ema_scan_kernel<<<rows, BLOCK, 0, stream>>>(x, y != nullptr ? w : w, y);
}